// Round 13
// baseline (87.105 us; speedup 1.0000x reference)
//
#include <hip/hip_runtime.h>
#include <hip/hip_bf16.h>
#include <hip/hip_fp8.h>
#include <math.h>

#define NB 4096     // batch (= B); label of row n is labels[n % NB]
#define NN 8192     // N = B * n_views
#define DD 128      // feature dim (bytes per fp8 row)
#define NCLS 100    // label values 0..99
#define NSPLIT 16   // j-splits; 512 cols per block
#define CHUNK 64    // cols per LDS-staged chunk
#define NCHUNK 8    // 512 / 64

constexpr float INV_T = 14.285714285714286f;   // 1/0.07 (= subtracted row max M)
constexpr float EC1   = 20.609929155556620f;   // INV_T * log2(e)
constexpr float EC0   = -20.609929155556620f;  // -INV_T * log2(e)
constexpr float LN2   = 0.6931471805599453f;

typedef unsigned char u8;
typedef __attribute__((ext_vector_type(8))) int   v8i;
typedef __attribute__((ext_vector_type(4))) int   v4i;
typedef __attribute__((ext_vector_type(4))) float f32x4;

// ---- kernel 1: L2-normalize rows -> fp8 e4m3 + selfdot of quantized row ----
__global__ __launch_bounds__(256) void k_norm(const float* __restrict__ feat,
                                              u8* __restrict__ fb8,
                                              float* __restrict__ selfdot,
                                              float* __restrict__ out) {
    const int gid = blockIdx.x * 256 + threadIdx.x;
    if (gid == 0) out[0] = 0.0f;               // k_final atomicAdds into out
    const int r    = gid >> 6;                 // one wave per row
    const int lane = threadIdx.x & 63;
    const float2 v = ((const float2*)(feat + (size_t)r * DD))[lane];
    float ss = v.x * v.x + v.y * v.y;
#pragma unroll
    for (int off = 1; off < 64; off <<= 1) ss += __shfl_xor(ss, off, 64);
    const float scale = 1.0f / fmaxf(sqrtf(ss), 1e-12f);
    const __hip_fp8_e4m3 qx(v.x * scale), qy(v.y * scale);  // OCP e4m3fn
    const unsigned short pack = (unsigned short)qx.__x |
                                ((unsigned short)qy.__x << 8);
    ((unsigned short*)(fb8 + (size_t)r * DD))[lane] = pack;
    // self-dot of the QUANTIZED row (matches the MFMA diagonal)
    const float xb = (float)qx, yb = (float)qy;
    float s2 = xb * xb + yb * yb;
#pragma unroll
    for (int off = 1; off < 64; off <<= 1) s2 += __shfl_xor(s2, off, 64);
    if (lane == 0) selfdot[r] = s2;
}

// stage one 64-col chunk's fp8 B-fragments into LDS, fragment-major, 2 waves.
// Pair p = jt*2 + half (8 pairs of 1 KB); wave w stages pairs 4w..4w+3.
// LDS dst = wave-uniform base + lane*16 (HW rule); per-lane GLOBAL address
// does the fragment gather: lane l wants row (jb+jt*16+(l&15)), bytes
// (l>>4)*32 + half*16.
__device__ __forceinline__ void stage_chunk(const u8* __restrict__ fb8, u8* sbuf,
                                            int jb, int w, int n15, int q) {
#pragma unroll
    for (int h = 0; h < 4; ++h) {
        const int p = w * 4 + h;
        const u8* g = fb8 + (size_t)(jb + (p >> 1) * 16 + n15) * DD + q * 32 + (p & 1) * 16;
        __builtin_amdgcn_global_load_lds(
            (const __attribute__((address_space(1))) void*)g,
            (__attribute__((address_space(3))) void*)(sbuf + p * 1024),
            16, 0, 0);
    }
}

// ---- kernel 2: F*F^T via MX-fp8 K=128 MFMA, fused exp + masked-possum ----
// Block: 64 rows x 512 cols, TWO waves of 32 rows (2-wave barriers = cheap
// drain; 18.4 KB LDS -> 8 independent blocks/CU so barrier gaps fill from
// other blocks). Grid 2048 = 128 rb x 16 js = exactly 8 rounds/CU.
// Per j-tile: 2 ds_read_b128 + 2 single-K MFMAs + 8-elem epilogue.
__global__ __launch_bounds__(128, 4) void k_main(const u8* __restrict__ fb8,
                                                 const int* __restrict__ labels,
                                                 float* __restrict__ g_se,
                                                 float* __restrict__ g_ps) {
    __shared__ u8 sB[2][CHUNK * DD];   // 2 x 8 KB, fragment-major
    __shared__ int slab[512];          // labels of this block's col range

    const int tid  = threadIdx.x;      // 0..127
    const int lane = tid & 63;
    const int w    = tid >> 6;                  // 0..1
    const int rb   = blockIdx.x >> 4;           // 0..127
    const int js   = blockIdx.x & (NSPLIT - 1); // 0..15
    const int i0   = rb * 64 + w * 32;
    const int jb0  = js * 512;
    const int q    = lane >> 4;
    const int n15  = lane & 15;

#pragma unroll
    for (int t = 0; t < 4; ++t)
        slab[tid + t * 128] = labels[(jb0 + tid + t * 128) & (NB - 1)];

    // A fragments: 2 row-tiles, full K=128 per tile (8 VGPRs each).
    // Operand layout: lane l holds A[row=l&15][k=(l>>4)*32 + 0..31].
    v8i af[2];
#pragma unroll
    for (int tt = 0; tt < 2; ++tt) {
        const u8* rp = fb8 + (size_t)(i0 + tt * 16 + n15) * DD + q * 32;
        const v4i lo = *(const v4i*)rp;
        const v4i hi = *(const v4i*)(rp + 16);
        v8i a;
#pragma unroll
        for (int k = 0; k < 4; ++k) { a[k] = lo[k]; a[4 + k] = hi[k]; }
        af[tt] = a;
    }
    // labels of this lane's 8 accumulator rows (C/D map: row = q*4+r)
    int labi[8];
#pragma unroll
    for (int tt = 0; tt < 2; ++tt)
#pragma unroll
        for (int r = 0; r < 4; ++r)
            labi[tt * 4 + r] = labels[(i0 + tt * 16 + q * 4 + r) & (NB - 1)];

    float a_se[8] = {}, a_ps[8] = {};

    stage_chunk(fb8, &sB[0][0], jb0, w, n15, q);
    __syncthreads();

    for (int c = 0; c < NCHUNK; ++c) {
        if (c + 1 < NCHUNK)
            stage_chunk(fb8, &sB[(c + 1) & 1][0], jb0 + (c + 1) * CHUNK, w, n15, q);
        const u8* sb = &sB[c & 1][0];
        const int crel = c * CHUNK;
#pragma unroll
        for (int jt = 0; jt < 4; ++jt) {
            const v4i lo = *(const v4i*)(sb + (jt * 2 + 0) * 1024 + lane * 16);
            const v4i hi = *(const v4i*)(sb + (jt * 2 + 1) * 1024 + lane * 16);
            v8i bb;
#pragma unroll
            for (int k = 0; k < 4; ++k) { bb[k] = lo[k]; bb[4 + k] = hi[k]; }
            const int labj = slab[crel + jt * 16 + n15];
            f32x4 a0 = {0.f, 0.f, 0.f, 0.f}, a1 = {0.f, 0.f, 0.f, 0.f};
            // cbsz=0 (A=fp8 e4m3), blgp=0 (B=fp8); scale bytes 0x7F = e8m0 1.0
            a0 = __builtin_amdgcn_mfma_scale_f32_16x16x128_f8f6f4(
                     af[0], bb, a0, 0, 0, 0, 0x7F7F7F7F, 0, 0x7F7F7F7F);
            a1 = __builtin_amdgcn_mfma_scale_f32_16x16x128_f8f6f4(
                     af[1], bb, a1, 0, 0, 0, 0x7F7F7F7F, 0, 0x7F7F7F7F);
#pragma unroll
            for (int r = 0; r < 4; ++r) {
                const float d0 = a0[r], d1 = a1[r];
                a_se[r]     += __builtin_amdgcn_exp2f(fmaf(d0, EC1, EC0));
                a_se[4 + r] += __builtin_amdgcn_exp2f(fmaf(d1, EC1, EC0));
                a_ps[r]     += (labi[r]     == labj) ? d0 : 0.0f;  // raw dot; shifted in k_final
                a_ps[4 + r] += (labi[4 + r] == labj) ? d1 : 0.0f;
            }
        }
        __syncthreads();
    }

    // 16 lanes per quad share the same rows; reduce, single plain store each
#pragma unroll
    for (int s = 0; s < 8; ++s) {
        float v1 = a_se[s], v2 = a_ps[s];
#pragma unroll
        for (int off = 1; off < 16; off <<= 1) {
            v1 += __shfl_xor(v1, off, 64);
            v2 += __shfl_xor(v2, off, 64);
        }
        if (n15 == 0) {
            const int row = i0 + (s >> 2) * 16 + q * 4 + (s & 3);
            g_se[js * NN + row] = v1;
            g_ps[js * NN + row] = v2;
        }
    }
}

// ---- kernel 3: per-row loss; counts via LDS histogram; atomic mean ----
__global__ __launch_bounds__(256) void k_final(const int* __restrict__ labels,
                                               const float* __restrict__ g_se,
                                               const float* __restrict__ g_ps,
                                               const float* __restrict__ selfdot,
                                               float* __restrict__ out) {
    __shared__ int hist[NCLS];
    const int tid = threadIdx.x;
    for (int i = tid; i < NCLS; i += 256) hist[i] = 0;
    __syncthreads();
    for (int b = tid; b < NB; b += 256) atomicAdd(&hist[labels[b]], 1);
    __syncthreads();

    const int r = blockIdx.x * 256 + tid;
    const int c = labels[r & (NB - 1)];
    float se = 0.f, ps = 0.f;
#pragma unroll
    for (int t = 0; t < NSPLIT; ++t) {
        se += g_se[t * NN + r];
        ps += g_ps[t * NN + r];
    }
    const float sd = selfdot[r];
    se -= __builtin_amdgcn_exp2f(fmaf(sd, EC1, EC0));  // drop diagonal from sumexp
    const float ct = (float)(2 * hist[c] - 1);         // positives excl. diagonal
    const float possum = INV_T * ((ps - sd) - ct);     // sum_pos (l_ij - M)
    const float lg  = __builtin_amdgcn_logf(se + 1e-12f) * LN2;
    const float mlpp = (possum - ct * lg) / fmaxf(ct, 1.0f);
    float v = -mlpp * (1.0f / (float)NN);
#pragma unroll
    for (int off = 1; off < 64; off <<= 1) v += __shfl_xor(v, off, 64);
    __shared__ float sred[4];
    if ((tid & 63) == 0) sred[tid >> 6] = v;
    __syncthreads();
    if (tid == 0) atomicAdd(out, sred[0] + sred[1] + sred[2] + sred[3]);
}

extern "C" void kernel_launch(void* const* d_in, const int* in_sizes, int n_in,
                              void* d_out, int out_size, void* d_ws, size_t ws_size,
                              hipStream_t stream) {
    const float* feat = (const float*)d_in[0];
    const int* labels = (const int*)d_in[1];
    float* out        = (float*)d_out;
    char* ws          = (char*)d_ws;

    u8* fb8         = (u8*)ws;                                       // 1 MB fp8
    float* g_se     = (float*)(ws + (size_t)1 * 1024 * 1024);        // [16][NN] 512 KB
    float* g_ps     = g_se + NSPLIT * NN;                            // 512 KB
    float* selfdot  = g_ps + NSPLIT * NN;                            // NN f32

    k_norm<<<NN / 4, 256, 0, stream>>>(feat, fb8, selfdot, out);
    k_main<<<(NN / 64) * NSPLIT, 128, 0, stream>>>(fb8, labels, g_se, g_ps);
    k_final<<<NN / 256, 256, 0, stream>>>(labels, g_se, g_ps, selfdot, out);
}